// Round 9
// baseline (163.631 us; speedup 1.0000x reference)
//
#include <hip/hip_runtime.h>
#include <hip/hip_bf16.h>
#include <stdint.h>

#define NROWS 8192
#define NF    1024
#define EPSV  1e-5f

typedef __attribute__((ext_vector_type(8))) short bf16x8;
typedef __attribute__((ext_vector_type(4))) float f32x4;

static __device__ __forceinline__ unsigned short f2bf(float v) {
    __hip_bfloat16 b = __float2bfloat16(v);
    return *reinterpret_cast<unsigned short*>(&b);
}
static __device__ __forceinline__ float bf2f(unsigned short u) {
    union { uint32_t i; float f; } cv; cv.i = (uint32_t)u << 16; return cv.f;
}

// ---- Kernel 1: transpose raw->bf16 [col][k] + per-block column stats ----
__global__ void transpose_stats(const float* __restrict__ X, const float* __restrict__ Y,
                                unsigned short* __restrict__ Xst, unsigned short* __restrict__ Yst,
                                float* __restrict__ psum, float* __restrict__ psq) {
    __shared__ unsigned short sbuf[64][68];
    int ct  = blockIdx.x;    // 0..15  column tile
    int rt  = blockIdx.y;    // 0..127 row tile (64 rows each)
    int mat = blockIdx.z;
    const float* A = mat ? Y : X;
    unsigned short* O = mat ? Yst : Xst;
    int tid = threadIdx.x;
    #pragma unroll
    for (int it = 0; it < 4; ++it) {
        int idx = it * 256 + tid;     // 0..1023
        int row = idx >> 4;           // 0..63
        int c4  = idx & 15;           // 0..15
        float4 v = *reinterpret_cast<const float4*>(
            A + (size_t)(rt * 64 + row) * NF + ct * 64 + c4 * 4);
        ushort4 o;
        o.x = f2bf(v.x); o.y = f2bf(v.y); o.z = f2bf(v.z); o.w = f2bf(v.w);
        *reinterpret_cast<ushort4*>(&sbuf[row][c4 * 4]) = o;
    }
    __syncthreads();
    {
        int c  = tid >> 2;            // 0..63 output column
        int r8 = tid & 3;             // 16-row group
        bf16x8 v0, v1;
        float s = 0.f, sq = 0.f;
        #pragma unroll
        for (int i = 0; i < 8; ++i) {
            unsigned short u = sbuf[r8 * 16 + i][c];
            v0[i] = (short)u;
            float f = bf2f(u); s += f; sq += f * f;
        }
        #pragma unroll
        for (int i = 0; i < 8; ++i) {
            unsigned short u = sbuf[r8 * 16 + 8 + i][c];
            v1[i] = (short)u;
            float f = bf2f(u); s += f; sq += f * f;
        }
        unsigned short* dst = O + (size_t)(ct * 64 + c) * NROWS + rt * 64 + r8 * 16;
        *reinterpret_cast<bf16x8*>(dst)     = v0;
        *reinterpret_cast<bf16x8*>(dst + 8) = v1;
        s  += __shfl_xor(s, 1);  s  += __shfl_xor(s, 2);
        sq += __shfl_xor(sq, 1); sq += __shfl_xor(sq, 2);
        if (r8 == 0) {
            int pidx = (mat * 128 + rt) * NF + ct * 64 + c;
            psum[pidx] = s;
            psq[pidx]  = sq;
        }
    }
}

// ---------------- Kernel 2: finalize mu / inv_sd ----------------
__global__ void stats_final(const float* __restrict__ psum, const float* __restrict__ psq,
                            float* __restrict__ mu, float* __restrict__ isd) {
    __shared__ float ls[4][64], lq[4][64];
    int mat  = blockIdx.y;
    int col0 = blockIdx.x * 64;          // 16 x-blocks
    int colq = threadIdx.x & 63;
    int g    = threadIdx.x >> 6;         // 4 groups of 32 chunks
    int col  = col0 + colq;
    float s = 0.f, sq = 0.f;
    #pragma unroll
    for (int k = 0; k < 32; ++k) {
        int idx = (mat * 128 + g * 32 + k) * NF + col;
        s  += psum[idx];
        sq += psq[idx];
    }
    ls[g][colq] = s; lq[g][colq] = sq;
    __syncthreads();
    if (g == 0) {
        s  = ls[0][colq] + ls[1][colq] + ls[2][colq] + ls[3][colq];
        sq = lq[0][colq] + lq[1][colq] + lq[2][colq] + lq[3][colq];
        float m   = s / (float)NROWS;
        float var = (sq - s * m) / (float)(NROWS - 1);
        var = fmaxf(var, 0.f);
        mu [mat * NF + col] = m;
        isd[mat * NF + col] = 1.0f / (sqrtf(var) + EPSV);
    }
}

// ---- Kernel 3: fused X/Y Gram GEMM, BK=32 dbuf pipeline, vmcnt(8) ----
// corr = isd*(G - n*mu*mu^T)*isd / n applied in epilogue; writes X-Y diff (bf16).
__global__ __launch_bounds__(256, 2) void gram_fused(
    const unsigned short* __restrict__ Xst, const unsigned short* __restrict__ Yst,
    const float* __restrict__ mu, const float* __restrict__ isd,
    unsigned short* __restrict__ Cdiff, int nsplit, int kper) {
    // 8 buffers of 128x32 bf16 (8KB): [0/1]=X-A dbuf, [2/3]=X-B, [4/5]=Y-A, [6/7]=Y-B
    __shared__ short lds[8][128 * 32];
    int nwg = 36 * nsplit, cpx = nwg >> 3;
    int bid = blockIdx.x;
    int swz = (bid & 7) * cpx + (bid >> 3);   // XCD-chunked (nwg % 8 == 0)
    int split = swz / 36, tile = swz % 36;
    int r = 0, t0 = tile;
    while (t0 >= 8 - r) { t0 -= 8 - r; ++r; }
    int c = r + t0;
    const short* Xs = reinterpret_cast<const short*>(Xst);
    const short* Ys = reinterpret_cast<const short*>(Yst);
    int tid = threadIdx.x, lane = tid & 63, wid = tid >> 6;
    int wr = wid >> 1, wc = wid & 1;
    f32x4 accX[4][4] = {}, accY[4][4] = {};
    int k0 = split * kper;
    int nstep = kper >> 5;                    // power of two
    // staging source slot pre-permuted by the inverse of the read swizzle
    int s8 = ((lane & 3) - (lane >> 3)) & 3;

    auto stage = [&](const short* M, short* bA, short* bB, int ts) {
        int kk = k0 + ts * 32;
        #pragma unroll
        for (int i = 0; i < 2; ++i) {
            int chunk = wid * 2 + i;              // 0..7, 16 rows each
            int rw = chunk * 16 + (lane >> 2);
            size_t ko = (size_t)kk + s8 * 8;
            const short* ga = M + (size_t)(r * 128 + rw) * NROWS + ko;
            __builtin_amdgcn_global_load_lds(
                (const __attribute__((address_space(1))) void*)ga,
                (__attribute__((address_space(3))) void*)(bA + chunk * 512), 16, 0, 0);
            const short* gb = M + (size_t)(c * 128 + rw) * NROWS + ko;
            __builtin_amdgcn_global_load_lds(
                (const __attribute__((address_space(1))) void*)gb,
                (__attribute__((address_space(3))) void*)(bB + chunk * 512), 16, 0, 0);
        }
    };
    auto compute = [&](const short* bA, const short* bB, f32x4 (&acc)[4][4]) {
        bf16x8 a[4], b[4];
        int rl = lane & 15;
        int sl = ((lane >> 4) + (rl >> 1)) & 3;   // read-side swizzle
        #pragma unroll
        for (int f = 0; f < 4; ++f) {
            a[f] = *reinterpret_cast<const bf16x8*>(bA + (wr * 64 + f * 16 + rl) * 32 + sl * 8);
            b[f] = *reinterpret_cast<const bf16x8*>(bB + (wc * 64 + f * 16 + rl) * 32 + sl * 8);
        }
        __builtin_amdgcn_s_setprio(1);
        #pragma unroll
        for (int fm = 0; fm < 4; ++fm)
            #pragma unroll
            for (int fn = 0; fn < 4; ++fn)
                acc[fm][fn] = __builtin_amdgcn_mfma_f32_16x16x32_bf16(
                    a[fm], b[fn], acc[fm][fn], 0, 0, 0);
        __builtin_amdgcn_s_setprio(0);
    };

    stage(Xs, lds[0], lds[2], 0);
    stage(Ys, lds[4], lds[6], 0);
    for (int t = 0; t < nstep; ++t) {
        int cur = t & 1, nxt = cur ^ 1;
        int tn = (t + 1) & (nstep - 1);           // dummy re-stage on last iter
        stage(Xs, lds[0 + nxt], lds[2 + nxt], tn);
        asm volatile("s_waitcnt vmcnt(8)" ::: "memory");   // X(t) landed
        __builtin_amdgcn_s_barrier();
        __builtin_amdgcn_sched_barrier(0);
        compute(lds[0 + cur], lds[2 + cur], accX);
        stage(Ys, lds[4 + nxt], lds[6 + nxt], tn);
        asm volatile("s_waitcnt vmcnt(8)" ::: "memory");   // Y(t) landed
        __builtin_amdgcn_s_barrier();
        __builtin_amdgcn_sched_barrier(0);
        compute(lds[4 + cur], lds[6 + cur], accY);
    }
    asm volatile("s_waitcnt vmcnt(0)" ::: "memory");       // drain dummy stages

    // epilogue: corrX - corrY partial for this split (bf16)
    const float* mux = mu;        const float* muy = mu  + NF;
    const float* isx = isd;       const float* isy = isd + NF;
    const float inv_n = 1.0f / (float)NROWS;
    float f0 = (split == 0) ? 1.0f : 0.0f;      // const term applied once
    float mxc[4], ixc[4], myc[4], iyc[4];
    #pragma unroll
    for (int fn = 0; fn < 4; ++fn) {
        int cf = c * 128 + wc * 64 + fn * 16 + (lane & 15);
        mxc[fn] = mux[cf]; ixc[fn] = isx[cf];
        myc[fn] = muy[cf]; iyc[fn] = isy[cf];
    }
    unsigned short* Cp = Cdiff + ((size_t)split * 36 + tile) * 16384;
    #pragma unroll
    for (int fm = 0; fm < 4; ++fm)
        #pragma unroll
        for (int reg = 0; reg < 4; ++reg) {
            int rf = r * 128 + wr * 64 + fm * 16 + (lane >> 4) * 4 + reg;
            float mxr = mux[rf], ixr = isx[rf];
            float myr = muy[rf], iyr = isy[rf];
            int rowl = wr * 64 + fm * 16 + (lane >> 4) * 4 + reg;
            #pragma unroll
            for (int fn = 0; fn < 4; ++fn) {
                float cx = (accX[fm][fn][reg] * inv_n - f0 * mxr * mxc[fn]) * ixr * ixc[fn];
                float cy = (accY[fm][fn][reg] * inv_n - f0 * myr * myc[fn]) * iyr * iyc[fn];
                int coll = wc * 64 + fn * 16 + (lane & 15);
                Cp[rowl * 128 + coll] = f2bf(cx - cy);
            }
        }
}

// ------- Kernel 4: masked squared-diff reduction -> loss (bf16 input) -------
__global__ void reduce_loss(const unsigned short* __restrict__ Cdiff, float* __restrict__ out,
                            int nsplit) {
    int tile = blockIdx.x, sub = blockIdx.y;   // sub: 16-row band
    int r = 0, t = tile;
    while (t >= 8 - r) { t -= 8 - r; ++r; }
    int c = r + t;
    float s = 0.f;
    for (int e4 = threadIdx.x; e4 < 512; e4 += 256) {   // 4-col units
        int row  = sub * 16 + (e4 >> 5);
        int col0 = (e4 & 31) * 4;
        float d0 = 0.f, d1 = 0.f, d2 = 0.f, d3 = 0.f;
        for (int sp = 0; sp < nsplit; ++sp) {
            ushort4 v = *reinterpret_cast<const ushort4*>(
                Cdiff + ((size_t)sp * 36 + tile) * 16384 + row * 128 + col0);
            d0 += bf2f(v.x); d1 += bf2f(v.y); d2 += bf2f(v.z); d3 += bf2f(v.w);
        }
        float dv[4] = {d0, d1, d2, d3};
        #pragma unroll
        for (int j = 0; j < 4; ++j) {
            int col = col0 + j;
            if (r == c && col <= row) continue;
            s += dv[j] * dv[j];
        }
    }
    #pragma unroll
    for (int off = 32; off > 0; off >>= 1) s += __shfl_down(s, off, 64);
    __shared__ float wsum[4];
    int lane = threadIdx.x & 63, wid = threadIdx.x >> 6;
    if (lane == 0) wsum[wid] = s;
    __syncthreads();
    if (threadIdx.x == 0) {
        float tot = wsum[0] + wsum[1] + wsum[2] + wsum[3];
        atomicAdd(out, tot * (1.0f / 523776.0f));
    }
}

extern "C" void kernel_launch(void* const* d_in, const int* in_sizes, int n_in,
                              void* d_out, int out_size, void* d_ws, size_t ws_size,
                              hipStream_t stream) {
    const float* X = (const float*)d_in[0];
    const float* Y = (const float*)d_in[1];
    char* ws = (char*)d_ws;

    // pick largest split-K that fits the workspace
    auto need = [](int ns) -> size_t {
        return ((size_t)32 << 20)                       // Xst + Yst
             + (size_t)ns * 36 * 16384 * 2              // Cdiff (bf16)
             + (size_t)2 * 128 * NF * 4 * 2             // psum + psq (2 MB)
             + (size_t)2 * NF * 4 * 2;                  // mu + isd
    };
    int nsplit = 16;
    if (ws_size < need(16)) nsplit = 8;
    if (ws_size < need(8))  nsplit = 4;
    int kper = NROWS / nsplit;

    unsigned short* Xst = (unsigned short*)(ws);
    unsigned short* Yst = (unsigned short*)(ws + ((size_t)16 << 20));
    unsigned short* Cdiff = (unsigned short*)(ws + ((size_t)32 << 20));
    size_t cd_sz = (size_t)nsplit * 36 * 16384 * 2;
    float* psum = (float*)(ws + ((size_t)32 << 20) + cd_sz);
    float* psq  = psum + 2 * 128 * NF;
    float* mu   = psq  + 2 * 128 * NF;
    float* isd  = mu   + 2 * NF;
    float* out  = (float*)d_out;

    hipMemsetAsync(out, 0, sizeof(float), stream);
    transpose_stats<<<dim3(16, 128, 2), 256, 0, stream>>>(X, Y, Xst, Yst, psum, psq);
    stats_final<<<dim3(16, 2), 256, 0, stream>>>(psum, psq, mu, isd);
    gram_fused<<<36 * nsplit, 256, 0, stream>>>(Xst, Yst, mu, isd, Cdiff, nsplit, kper);
    reduce_loss<<<dim3(36, 8), 256, 0, stream>>>(Cdiff, out, nsplit);
}